// Round 12
// baseline (877.941 us; speedup 1.0000x reference)
//
#include <hip/hip_runtime.h>
#include <math.h>

static constexpr int BT  = 512;    // batch
static constexpr int TT  = 2048;   // time steps

// f64-derived constants, cast to f32 exactly as the reference does
static constexpr float C00 = (float)(1000.0 / (1.0 - 0.09));            // D[0][0]
static constexpr float C01 = (float)((1000.0 / (1.0 - 0.09)) * 0.3);    // D[0][1]
static constexpr float C22 = (float)((1000.0 / (1.0 - 0.09)) * 0.35);   // D[2][2]
static constexpr float INV3GH = (float)(1.0 / (3.0 * (1000.0 / 2.6) + 100.0));
static constexpr float SQ3 = 1.7320508075688772f;
static constexpr float IR3 = 0.57735026918962576f;

__device__ __forceinline__ float softplus_f(float v) {
    return fmaxf(v, 0.0f) + log1pf(expf(-fabsf(v)));
}

// ---------------------------------------------------------------------------
// Fully fused, TWO batch rows per block (16 waves): waves 0-7 -> b0's eight
// chains, waves 8-15 -> b1's. Grid 256 -> 2 blocks/CU possible (32 waves/CU)
// when VGPR <= 64, which __launch_bounds__(1024,8) targets. Waves write raw
// stress to red[t][25]; 384 reduce-threads per b do the 24-FMA W2 dot from
// LDS (removes the 18-reg w2r cache that blocked the 64-VGPR budget).
// ---------------------------------------------------------------------------
__global__ __launch_bounds__(1024, 8) void k_fused(
    const float* __restrict__ x, const float* __restrict__ W11,
    const float* __restrict__ W12, const float* __restrict__ W2,
    float* __restrict__ out)
{
    __shared__ __align__(16) float w11s[16 * 36];      // [2p+h][36]
    __shared__ __align__(16) float w12d[24 * 36];      // [3p+j][36], D & sqrt3
    __shared__ float w2s[144];                         // softplus, xy col * IR3
    __shared__ __align__(16) float xs[2][2][64 * 36];  // [bsel][buf][t][36]
    __shared__ float red[2][64 * 25];                  // [bsel][t][p*3+c]

    const int tid  = threadIdx.x;
    const int lane = tid & 63;          // t within window
    const int wv   = (tid >> 6) & 7;    // p (0..7)
    const int bsel = tid >> 9;          // 0 or 1
    const int ltid = tid & 511;         // thread id within this b's half
    const int b    = blockIdx.x * 2 + bsel;

    // ---- prologue: weights into LDS (1024 threads) ----
    if (tid < 512) w11s[(tid >> 5) * 36 + (tid & 31)] = W11[tid];
    else if (tid < 768) {
        int i = tid - 512 + 512;
        w11s[(i >> 5) * 36 + (i & 31)] = W11[i];
    }
    if (tid < 768) {
        int r = tid >> 5, fc = tid & 31;
        int p = r / 3, j = r - p * 3;
        const float* wb = W12 + p * 96 + fc;
        float v;
        if (j == 0)      v = C00 * wb[0]  + C01 * wb[32];
        else if (j == 1) v = C01 * wb[0]  + C00 * wb[32];
        else             v = (C22 * wb[64]) * SQ3;
        w12d[r * 36 + fc] = v;
    }
    if (tid >= 768 && tid < 912) {
        int i = tid - 768;
        float v = softplus_f(W2[i]);
        if ((i % 24) % 3 == 2) v *= IR3;
        w2s[i] = v;
    }
    // stage window 0 for this thread's b
    const float4* xb = (const float4*)x + (size_t)b * (TT * 8);
    {
        float4 val = xb[ltid];
        int t = ltid >> 3, c = ltid & 7;
        *(float4*)&xs[bsel][0][t * 36 + 4 * c] = val;
    }
    __syncthreads();

    const float4* wa0 = (const float4*)(w11s + (2 * wv) * 36);
    const float4* wa1 = (const float4*)(w11s + (2 * wv + 1) * 36);
    const float4* wb0 = (const float4*)(w12d + (3 * wv) * 36);
    const float4* wb1 = (const float4*)(w12d + (3 * wv + 1) * 36);
    const float4* wb2 = (const float4*)(w12d + (3 * wv + 2) * 36);

    float Pxx = 0.f, Pyy = 0.f, Pxy = 0.f;
    float sigY = 10.f, sigY2 = 100.f, d0 = 0.f;

    for (int w = 0; w < 32; ++w) {
        // issue next window's x load early
        float4 nval;
        const bool have = (w < 31);
        if (have) nval = xb[(w + 1) * 512 + ltid];

        // ---- projection for (chain b*8+wv, t = w*64+lane) ----
        const float* xr = &xs[bsel][w & 1][lane * 36];
        float dn = 0.f, ds = 0.f, e0 = 0.f, e1 = 0.f, e2 = 0.f;
        #pragma unroll
        for (int c = 0; c < 8; ++c) {
            float4 xf = *(const float4*)(xr + 4 * c);
            float4 a0 = wa0[c], a1 = wa1[c];
            float4 b0 = wb0[c], b1 = wb1[c], b2 = wb2[c];
            dn = fmaf(xf.x, a0.x, dn); dn = fmaf(xf.y, a0.y, dn);
            dn = fmaf(xf.z, a0.z, dn); dn = fmaf(xf.w, a0.w, dn);
            ds = fmaf(xf.x, a1.x, ds); ds = fmaf(xf.y, a1.y, ds);
            ds = fmaf(xf.z, a1.z, ds); ds = fmaf(xf.w, a1.w, ds);
            e0 = fmaf(xf.x, b0.x, e0); e0 = fmaf(xf.y, b0.y, e0);
            e0 = fmaf(xf.z, b0.z, e0); e0 = fmaf(xf.w, b0.w, e0);
            e1 = fmaf(xf.x, b1.x, e1); e1 = fmaf(xf.y, b1.y, e1);
            e1 = fmaf(xf.z, b1.z, e1); e1 = fmaf(xf.w, b1.w, e1);
            e2 = fmaf(xf.x, b2.x, e2); e2 = fmaf(xf.y, b2.y, e2);
            e2 = fmaf(xf.z, b2.z, e2); e2 = fmaf(xf.w, b2.w, e2);
        }
        float dnp  = fmaxf(dn, 0.f);
        float lam  = sqrtf(fmaf(dnp, dnp, fmaf(ds, ds, 1e-12f)));
        float dnew = (0.1f * (lam - 0.01f)) / (lam * 0.09f);
        dnew = fminf(fmaxf(dnew, 0.f), 1.f);

        // ---- window-parallel plastic scan (verified R10/R11 flow) ----
        float sxx = e0 - Pxx, syy = e1 - Pyy, sxy = e2 - Pxy;
        float q = fmaf(sxy, sxy, 1e-12f);   // sxy sqrt3-scaled
        q = fmaf(syy, syy, q);
        q = fmaf(sxx, sxx - syy, q);
        float f = 1.0f;

        unsigned long long mask = __ballot(q > sigY2);
        while (mask) {
            int ts = __ffsll((long long)mask) - 1;
            float qs  = __shfl(q, ts);
            float sxs = __shfl(sxx, ts);
            float sys = __shfl(syy, ts);
            float sps = __shfl(sxy, ts);
            float rq  = __builtin_amdgcn_rsqf(qs);
            float seq = qs * rq;
            float dk  = (seq - sigY) * INV3GH;
            float fn  = fmaf(100.f, dk, sigY);
            float fs  = fn * rq;
            float om  = 1.0f - fs;
            Pxx = fmaf(om, sxs, Pxx);
            Pyy = fmaf(om, sys, Pyy);
            Pxy = fmaf(om, sps, Pxy);
            sigY = fn; sigY2 = fn * fn;
            if (lane == ts) f = fs;
            bool redo = lane > ts;
            if (redo) {
                sxx = e0 - Pxx; syy = e1 - Pyy; sxy = e2 - Pxy;
                q = fmaf(sxy, sxy, 1e-12f);
                q = fmaf(syy, syy, q);
                q = fmaf(sxx, sxx - syy, q);
            }
            mask = __ballot(redo && (q > sigY2));
        }

        // damage: exclusive max-scan seeded by d0
        float m = dnew;
        #pragma unroll
        for (int off = 1; off < 64; off <<= 1) {
            float t2 = __shfl_up(m, off);
            if (lane >= off) m = fmaxf(m, t2);
        }
        float de = __shfl_up(m, 1);
        de = (lane == 0) ? d0 : fmaxf(d0, de);
        bool loading = dnew > de;
        float di = fmaxf(de, dnew);
        d0 = fmaxf(d0, __shfl(m, 63));

        float scale = loading ? f : f * (1.0f - di);

        // ---- raw stress -> red[t][p*3..] ----
        float* rr = &red[bsel][lane * 25 + wv * 3];
        rr[0] = scale * sxx; rr[1] = scale * syy; rr[2] = scale * sxy;
        __syncthreads();

        // ---- reduce: 384 threads per b do the 24-FMA W2 dot ----
        if (ltid < 384) {
            int t = ltid & 63, k = ltid >> 6;
            const float* rp = &red[bsel][t * 25];
            const float* wk = &w2s[k * 24];
            float acc = 0.f;
            #pragma unroll
            for (int j = 0; j < 24; ++j) acc = fmaf(rp[j], wk[j], acc);
            out[((size_t)b * TT + w * 64 + t) * 6 + k] = acc;
        }
        // write next window's stage (disjoint buffer)
        if (have) {
            int t = ltid >> 3, c = ltid & 7;
            *(float4*)&xs[bsel][(w + 1) & 1][t * 36 + 4 * c] = nval;
        }
        __syncthreads();   // red reusable + xs[(w+1)&1] ready
    }
}

extern "C" void kernel_launch(void* const* d_in, const int* in_sizes, int n_in,
                              void* d_out, int out_size, void* d_ws, size_t ws_size,
                              hipStream_t stream)
{
    const float* x   = (const float*)d_in[0];
    const float* W11 = (const float*)d_in[1];
    const float* W12 = (const float*)d_in[2];
    const float* W2  = (const float*)d_in[3];
    float* out = (float*)d_out;

    hipLaunchKernelGGL(k_fused, dim3(BT / 2), dim3(1024), 0, stream,
                       x, W11, W12, W2, out);
}

// Round 13
// 141.981 us; speedup vs baseline: 6.1835x; 6.1835x over previous
//
#include <hip/hip_runtime.h>
#include <math.h>

static constexpr int BT  = 512;    // batch
static constexpr int TT  = 2048;   // time steps

// f64-derived constants, cast to f32 exactly as the reference does
static constexpr float C00 = (float)(1000.0 / (1.0 - 0.09));            // D[0][0]
static constexpr float C01 = (float)((1000.0 / (1.0 - 0.09)) * 0.3);    // D[0][1]
static constexpr float C22 = (float)((1000.0 / (1.0 - 0.09)) * 0.35);   // D[2][2]
static constexpr float INV3GH = (float)(1.0 / (3.0 * (1000.0 / 2.6) + 100.0));
static constexpr float SQ3 = 1.7320508075688772f;
static constexpr float IR3 = 0.57735026918962576f;

typedef float f2 __attribute__((ext_vector_type(2)));

__device__ __forceinline__ float softplus_f(float v) {
    return fmaxf(v, 0.0f) + log1pf(expf(-fabsf(v)));
}

// ---------------------------------------------------------------------------
// Fully fused (R11 structure): one b per 512-thread block; wave = p, lane = t.
// R13 deltas: (1) ping-pong red + reduce of window w-1 overlapped into
// window w -> ONE barrier per window; (2) projection accumulators packed as
// float2 (v_pk_fma_f32), halving the 160-FMA block's issue count.
// ---------------------------------------------------------------------------
__global__ __launch_bounds__(512) void k_fused(
    const float* __restrict__ x, const float* __restrict__ W11,
    const float* __restrict__ W12, const float* __restrict__ W2,
    float* __restrict__ out)
{
    __shared__ __align__(16) float w11s[16 * 36];   // [2p+h][36]
    __shared__ __align__(16) float w12d[24 * 36];   // [3p+j][36], D & sqrt3 folded
    __shared__ float w2s[144];                      // softplus(W2), xy col * IR3
    __shared__ __align__(16) float xs[2][64 * 36];  // double-buffered x window
    __shared__ __align__(16) float red[2][64 * 52]; // ping-pong [t][k*8+p]

    const int tid  = threadIdx.x;
    const int lane = tid & 63;     // t within window
    const int wv   = tid >> 6;     // p (0..7)
    const int b    = blockIdx.x;

    // ---- prologue: weights into LDS ----
    if (tid < 512) w11s[(tid >> 5) * 36 + (tid & 31)] = W11[tid];
    if (tid < 256) {
        int i = tid + 512;
        w11s[(i >> 5) * 36 + (i & 31)] = W11[i];
    }
    for (int i = tid; i < 768; i += 512) {
        int r = i >> 5, fc = i & 31;
        int p = r / 3, j = r - p * 3;
        const float* wb = W12 + p * 96 + fc;
        float v;
        if (j == 0)      v = C00 * wb[0]  + C01 * wb[32];
        else if (j == 1) v = C01 * wb[0]  + C00 * wb[32];
        else             v = (C22 * wb[64]) * SQ3;
        w12d[r * 36 + fc] = v;
    }
    if (tid < 144) {
        float v = softplus_f(W2[tid]);
        if ((tid % 24) % 3 == 2) v *= IR3;
        w2s[tid] = v;
    }
    // stage window 0
    const float4* xg4 = (const float4*)x + (size_t)b * (TT * 8);
    {
        float4 val = xg4[tid];
        int t = tid >> 3, c = tid & 7;
        *(float4*)&xs[0][t * 36 + 4 * c] = val;
    }
    __syncthreads();

    // wave-uniform W2 columns for this p
    float w2r0[6], w2r1[6], w2r2[6];
    #pragma unroll
    for (int k = 0; k < 6; ++k) {
        w2r0[k] = w2s[k * 24 + 3 * wv];
        w2r1[k] = w2s[k * 24 + 3 * wv + 1];
        w2r2[k] = w2s[k * 24 + 3 * wv + 2];
    }
    const float4* wa0 = (const float4*)(w11s + (2 * wv) * 36);
    const float4* wa1 = (const float4*)(w11s + (2 * wv + 1) * 36);
    const float4* wb0 = (const float4*)(w12d + (3 * wv) * 36);
    const float4* wb1 = (const float4*)(w12d + (3 * wv + 1) * 36);
    const float4* wb2 = (const float4*)(w12d + (3 * wv + 2) * 36);

    float Pxx = 0.f, Pyy = 0.f, Pxy = 0.f;
    float sigY = 10.f, sigY2 = 100.f, d0 = 0.f;

    for (int w = 0; w < 32; ++w) {
        // issue next window's x load early (latency hides under compute)
        float4 nval;
        const bool have = (w < 31);
        if (have) nval = xg4[(w + 1) * 512 + tid];

        // ---- projection, packed f32 pairs (v_pk_fma) ----
        const float* xr = &xs[w & 1][lane * 36];
        f2 dn2 = {0.f, 0.f}, ds2 = {0.f, 0.f};
        f2 e02 = {0.f, 0.f}, e12 = {0.f, 0.f}, e22 = {0.f, 0.f};
        #pragma unroll
        for (int c = 0; c < 8; ++c) {
            float4 xf = *(const float4*)(xr + 4 * c);
            float4 a0 = wa0[c], a1 = wa1[c];
            float4 b0 = wb0[c], b1 = wb1[c], b2 = wb2[c];
            f2 xlo = {xf.x, xf.y}, xhi = {xf.z, xf.w};
            f2 t0, t1;
            t0 = (f2){a0.x, a0.y}; t1 = (f2){a0.z, a0.w};
            dn2 = xlo * t0 + dn2;  dn2 = xhi * t1 + dn2;
            t0 = (f2){a1.x, a1.y}; t1 = (f2){a1.z, a1.w};
            ds2 = xlo * t0 + ds2;  ds2 = xhi * t1 + ds2;
            t0 = (f2){b0.x, b0.y}; t1 = (f2){b0.z, b0.w};
            e02 = xlo * t0 + e02;  e02 = xhi * t1 + e02;
            t0 = (f2){b1.x, b1.y}; t1 = (f2){b1.z, b1.w};
            e12 = xlo * t0 + e12;  e12 = xhi * t1 + e12;
            t0 = (f2){b2.x, b2.y}; t1 = (f2){b2.z, b2.w};
            e22 = xlo * t0 + e22;  e22 = xhi * t1 + e22;
        }
        float dn = dn2.x + dn2.y, ds = ds2.x + ds2.y;
        float e0 = e02.x + e02.y, e1 = e12.x + e12.y, e2 = e22.x + e22.y;

        float dnp  = fmaxf(dn, 0.f);
        float lam  = sqrtf(fmaf(dnp, dnp, fmaf(ds, ds, 1e-12f)));
        float dnew = (0.1f * (lam - 0.01f)) / (lam * 0.09f);
        dnew = fminf(fmaxf(dnew, 0.f), 1.f);

        // ---- window-parallel plastic scan (verified R10/R11 flow) ----
        float sxx = e0 - Pxx, syy = e1 - Pyy, sxy = e2 - Pxy;
        float q = fmaf(sxy, sxy, 1e-12f);   // sxy sqrt3-scaled
        q = fmaf(syy, syy, q);
        q = fmaf(sxx, sxx - syy, q);
        float f = 1.0f;

        unsigned long long mask = __ballot(q > sigY2);
        while (mask) {
            int ts = __ffsll((long long)mask) - 1;
            float qs  = __shfl(q, ts);
            float sxs = __shfl(sxx, ts);
            float sys = __shfl(syy, ts);
            float sps = __shfl(sxy, ts);
            float rq  = __builtin_amdgcn_rsqf(qs);
            float seq = qs * rq;
            float dk  = (seq - sigY) * INV3GH;
            float fn  = fmaf(100.f, dk, sigY);
            float fs  = fn * rq;
            float om  = 1.0f - fs;
            Pxx = fmaf(om, sxs, Pxx);
            Pyy = fmaf(om, sys, Pyy);
            Pxy = fmaf(om, sps, Pxy);
            sigY = fn; sigY2 = fn * fn;
            if (lane == ts) f = fs;
            bool redo = lane > ts;
            if (redo) {
                sxx = e0 - Pxx; syy = e1 - Pyy; sxy = e2 - Pxy;
                q = fmaf(sxy, sxy, 1e-12f);
                q = fmaf(syy, syy, q);
                q = fmaf(sxx, sxx - syy, q);
            }
            mask = __ballot(redo && (q > sigY2));
        }

        // damage: exclusive max-scan seeded by d0
        float m = dnew;
        #pragma unroll
        for (int off = 1; off < 64; off <<= 1) {
            float t2 = __shfl_up(m, off);
            if (lane >= off) m = fmaxf(m, t2);
        }
        float de = __shfl_up(m, 1);
        de = (lane == 0) ? d0 : fmaxf(d0, de);
        bool loading = dnew > de;
        float di = fmaxf(de, dnew);
        d0 = fmaxf(d0, __shfl(m, 63));

        float scale = loading ? f : f * (1.0f - di);
        float o0 = scale * sxx, o1 = scale * syy, o2 = scale * sxy;

        // ---- per-wave W2 partials -> red[w&1][t][k*8+p] ----
        #pragma unroll
        for (int k = 0; k < 6; ++k) {
            float cpk = fmaf(o0, w2r0[k], fmaf(o1, w2r1[k], o2 * w2r2[k]));
            red[w & 1][lane * 52 + k * 8 + wv] = cpk;
        }

        // ---- overlapped reduce of the PREVIOUS window ----
        if (w > 0 && tid < 384) {
            int t = tid & 63, k = tid >> 6;
            const float4* rp4 = (const float4*)&red[(w - 1) & 1][t * 52 + k * 8];
            float4 a = rp4[0], bb = rp4[1];
            float acc = ((a.x + a.y) + (a.z + a.w))
                      + ((bb.x + bb.y) + (bb.z + bb.w));
            out[((size_t)b * TT + (w - 1) * 64 + t) * 6 + k] = acc;
        }

        // write next window's stage (disjoint buffer)
        if (have) {
            int t = tid >> 3, c = tid & 7;
            *(float4*)&xs[(w + 1) & 1][t * 36 + 4 * c] = nval;
        }
        __syncthreads();   // the ONLY barrier per window
    }

    // epilogue: reduce window 31
    if (tid < 384) {
        int t = tid & 63, k = tid >> 6;
        const float4* rp4 = (const float4*)&red[1][t * 52 + k * 8];
        float4 a = rp4[0], bb = rp4[1];
        float acc = ((a.x + a.y) + (a.z + a.w))
                  + ((bb.x + bb.y) + (bb.z + bb.w));
        out[((size_t)b * TT + 31 * 64 + t) * 6 + k] = acc;
    }
}

extern "C" void kernel_launch(void* const* d_in, const int* in_sizes, int n_in,
                              void* d_out, int out_size, void* d_ws, size_t ws_size,
                              hipStream_t stream)
{
    const float* x   = (const float*)d_in[0];
    const float* W11 = (const float*)d_in[1];
    const float* W12 = (const float*)d_in[2];
    const float* W2  = (const float*)d_in[3];
    float* out = (float*)d_out;

    hipLaunchKernelGGL(k_fused, dim3(BT), dim3(512), 0, stream,
                       x, W11, W12, W2, out);
}